// Round 2
// baseline (467.750 us; speedup 1.0000x reference)
//
#include <hip/hip_runtime.h>

#define NEDGES 20000
#define KMAX 16
#define NTRIP (NEDGES*KMAX)
#define EMB 128
#define INTERM 64
#define NSPH 7
#define UNITS 128
#define KSTEPS 256               // K = 8192 / 32

#define SC_BLOCKS (NTRIP/256)    // 1250
#define W_BLOCKS  512
#define RP_BLOCKS (NEDGES/4)     // 5000

typedef __attribute__((ext_vector_type(8))) short short8;
typedef __attribute__((ext_vector_type(4))) float floatx4;
typedef __attribute__((ext_vector_type(2))) float v2f;

__device__ __forceinline__ unsigned bf16pair(float a, float b) {
    unsigned ua = __float_as_uint(a), ub = __float_as_uint(b);
    ua = (ua + 0x7fffu + ((ua >> 16) & 1u)) >> 16;
    ub = (ub + 0x7fffu + ((ub >> 16) & 1u)) & 0xffff0000u;
    return ua | ub;
}
__device__ __forceinline__ v2f splat2(float f) { v2f r; r.x = f; r.y = f; return r; }

// Conflict-free a_s unit map. Within each frag-row of 64 uint4, element
// (row 0..15, koct 0..3) lives at unit = 8*(row>>1) + L, L chosen so that
// both the writer pattern (row fixed, koct+arow vary per 16 lanes) and the
// reader pattern (koct fixed, row varies per 16 lanes) spread exactly 2
// lanes per 16B bank-group (2-way = free). Bijective: given (row>>1, L)
// recover (koct, row&1) uniquely.
__device__ __forceinline__ int aunit(int row, int koct) {
    int y = row >> 1;
    return y * 8 + ((4 * (koct & 1) + (koct >> 1) + y + 2 * (row & 1)) & 7);
}

// prep roles: [0,1250) scatter-inverse; [1250,1762) weight->bf16 B-frags;
// [1762, 6762) rbf fp32 (e,i,7) -> bf16-padded rpad[e][i] (8 bf16 = uint4).
// No memset needed: (id_reduce,Kidx) pairs cover all slots; fused_all also
// bounds-checks t.
__global__ __launch_bounds__(256)
void prep(const int* __restrict__ idr, const int* __restrict__ kix,
          int* __restrict__ inv, const float* __restrict__ w,
          uint4* __restrict__ w2f, const float* __restrict__ rbf,
          uint4* __restrict__ rpad) {
    const int b = blockIdx.x, tid = threadIdx.x;
    if (b < SC_BLOCKS) {
        int t = b * 256 + tid;
        int e = idr[t], k = kix[t];
        if ((unsigned)e < NEDGES && (unsigned)k < KMAX)
            inv[e * KMAX + k] = t;
    } else if (b < SC_BLOCKS + W_BLOCKS) {
        // weight (emb, interm, o) fp32 -> bf16 MFMA B-fragment order.
        // uint4 idx = (nt*256 + ks)*64 + lane; elem j: k = ks*32 + (lane>>4)*8 + j,
        // o = nt*16 + (lane&15); k = i*128 + emb.
        int idx  = (b - SC_BLOCKS) * 256 + tid;
        int lane = idx & 63;
        int ks   = (idx >> 6) & 255;
        int nt   = idx >> 14;
        int o  = nt * 16 + (lane & 15);
        int kb = ks * 32 + (lane >> 4) * 8;
        unsigned pk[4];
#pragma unroll
        for (int jj = 0; jj < 4; ++jj) {
            int k0 = kb + 2 * jj;
            int i0 = k0 >> 7, em0 = k0 & 127;
            int i1 = (k0 + 1) >> 7, em1 = (k0 + 1) & 127;
            float f0 = w[((size_t)em0 * INTERM + i0) * UNITS + o];
            float f1 = w[((size_t)em1 * INTERM + i1) * UNITS + o];
            pk[jj] = bf16pair(f0, f1);
        }
        w2f[idx] = make_uint4(pk[0], pk[1], pk[2], pk[3]);
    } else {
        // rpad: thread (e = rb*4 + tid>>6, i = tid&63). Wave reads 1792B
        // contiguous rbf, writes 1KB contiguous rpad.
        int rb = b - (SC_BLOCKS + W_BLOCKS);
        int e = rb * 4 + (tid >> 6), i = tid & 63;
        const float* rs = rbf + (size_t)e * 448 + i * 7;
        float s0 = rs[0], s1 = rs[1], s2 = rs[2], s3 = rs[3];
        float s4 = rs[4], s5 = rs[5], s6 = rs[6];
        rpad[(size_t)e * 64 + i] = make_uint4(bf16pair(s0, s1), bf16pair(s2, s3),
                                              bf16pair(s4, s5), bf16pair(s6, 0.f));
    }
}

// fused_all: block = 32 edges x N=128 x full K. 512 threads (8 waves, wave = nt).
// Prologue: per-thread sum_k slice skf[7][8] accumulated from m/sph via inv
// (4-deep software-pipelined m gather). Main loop: 64 chunks of one interm i;
// A-frags built from rpad (register, 3-chunks-ahead prefetch) + skf into a
// conflict-free-swizzled LDS double buffer; B-frags (w2f) loaded post-barrier
// so no in-flight vmem is drained by __syncthreads.
__global__ __launch_bounds__(512, 4)
void fused_all(const float* __restrict__ sph, const float* __restrict__ m,
               const int* __restrict__ inv, const uint4* __restrict__ w2f,
               const uint4* __restrict__ rpad, float* __restrict__ out) {
    __shared__ uint4 a_s[2][520];               // 16640 B, frag-row stride 65
    int*   inv_s = (int*)a_s;                   // prologue scratch: 2048 B
    float* sph_s = (float*)((char*)a_s + 2048); // prologue scratch: 14336 B

    const int tid = threadIdx.x;
    const size_t e0 = (size_t)blockIdx.x * 32;
    const int lane = tid & 63, wid = tid >> 6;   // wid = nt 0..7
    const int e = tid >> 4, oct = tid & 15;      // e 0..31

    // writer target in a_s: arow = (e>>4)*4 + (oct>>2), swizzled unit
    const int wua = ((e >> 4) * 4 + (oct >> 2)) * 65 + aunit(e & 15, oct & 3);
    // reader unit (per-lane constant, same for every ksl/half)
    const int runit = aunit(lane & 15, lane >> 4);

    // stage inv + sph into scratch
    inv_s[tid] = inv[e0 * 16 + tid];
    for (int j = tid; j < 32 * 112; j += 512) sph_s[j] = sph[e0 * 112 + j];
    __syncthreads();

    // fused build_sumk: skf[s][h] = sum_k sph[e][s][k] * m[inv[e][k]][oct*8+2h..+1]
    // 4-deep software pipeline on the gathered m rows.
    v2f skf[NSPH][4];
#pragma unroll
    for (int s = 0; s < NSPH; ++s)
#pragma unroll
        for (int h = 0; h < 4; ++h) skf[s][h] = splat2(0.f);
    {
        const float4* mrow = (const float4*)m;
        const int* ip = inv_s + e * 16;
        const float* sp = sph_s + e * 112;
        float4 pb[4][2];
#pragma unroll
        for (int k = 0; k < 4; ++k) {
            int t = ip[k];
            pb[k][0] = make_float4(0.f, 0.f, 0.f, 0.f);
            pb[k][1] = make_float4(0.f, 0.f, 0.f, 0.f);
            if ((unsigned)t < (unsigned)NTRIP) {
                const float4* tp = mrow + (size_t)t * 32 + oct * 2;
                pb[k][0] = tp[0];
                pb[k][1] = tp[1];
            }
        }
#pragma unroll
        for (int k = 0; k < 16; ++k) {
            const int sl = k & 3;
            float4 v0 = pb[sl][0], v1 = pb[sl][1];
            if (k < 12) {
                int t = ip[k + 4];
                pb[sl][0] = make_float4(0.f, 0.f, 0.f, 0.f);
                pb[sl][1] = make_float4(0.f, 0.f, 0.f, 0.f);
                if ((unsigned)t < (unsigned)NTRIP) {
                    const float4* tp = mrow + (size_t)t * 32 + oct * 2;
                    pb[sl][0] = tp[0];
                    pb[sl][1] = tp[1];
                }
            }
            v2f mv[4];
            mv[0].x = v0.x; mv[0].y = v0.y;
            mv[1].x = v0.z; mv[1].y = v0.w;
            mv[2].x = v1.x; mv[2].y = v1.y;
            mv[3].x = v1.z; mv[3].y = v1.w;
#pragma unroll
            for (int s = 0; s < NSPH; ++s) {
                float cs = sp[s * 16 + k];
#pragma unroll
                for (int h = 0; h < 4; ++h)
                    skf[s][h] = __builtin_elementwise_fma(splat2(cs), mv[h], skf[s][h]);
            }
        }
    }

    // B-frag (chunk 0) + rbf prefetch; chunk x uses rp slot x&1 (x>=1), rpA for 0
    floatx4 acc[2] = {{0.f, 0.f, 0.f, 0.f}, {0.f, 0.f, 0.f, 0.f}};
    uint4 wf[4];
    const uint4* wbase = w2f + ((size_t)wid * KSTEPS) * 64 + lane;
#pragma unroll
    for (int ksl = 0; ksl < 4; ++ksl) wf[ksl] = wbase[(size_t)ksl * 64];
    const uint4* rp_g = rpad + (e0 + e) * 64;
    uint4 rpA = rp_g[0], rpB = rp_g[1];

    auto buildChunk = [&](const uint4 rv4, uint4* dstbuf) {
        float rv[NSPH];
        rv[0] = __uint_as_float(rv4.x << 16);
        rv[1] = __uint_as_float(rv4.x & 0xffff0000u);
        rv[2] = __uint_as_float(rv4.y << 16);
        rv[3] = __uint_as_float(rv4.y & 0xffff0000u);
        rv[4] = __uint_as_float(rv4.z << 16);
        rv[5] = __uint_as_float(rv4.z & 0xffff0000u);
        rv[6] = __uint_as_float(rv4.w << 16);
        v2f v[4];
#pragma unroll
        for (int h = 0; h < 4; ++h) v[h] = splat2(rv[0]) * skf[0][h];
#pragma unroll
        for (int s = 1; s < NSPH; ++s)
#pragma unroll
            for (int h = 0; h < 4; ++h)
                v[h] = __builtin_elementwise_fma(splat2(rv[s]), skf[s][h], v[h]);
        dstbuf[wua] = make_uint4(bf16pair(v[0].x, v[0].y), bf16pair(v[1].x, v[1].y),
                                 bf16pair(v[2].x, v[2].y), bf16pair(v[3].x, v[3].y));
    };

    __syncthreads();            // scratch (inv_s/sph_s) dead; a_s reusable
    buildChunk(rpA, a_s[0]);    // chunk 0
    rpA = rp_g[2];              // refill slot 0 with chunk 2
    __syncthreads();

    auto body = [&](int c, uint4& rpSlot) {
        const int cur = c & 1, nxt = cur ^ 1;
        if (c < 63) {
            buildChunk(rpSlot, a_s[nxt]);           // chunk c+1
            if (c < 61) rpSlot = rp_g[c + 3];       // prefetch chunk c+3
        }
#pragma unroll
        for (int ksl = 0; ksl < 4; ++ksl) {
            short8 a0 = __builtin_bit_cast(short8, a_s[cur][ksl * 65 + runit]);
            short8 a1 = __builtin_bit_cast(short8, a_s[cur][(4 + ksl) * 65 + runit]);
            short8 bb = __builtin_bit_cast(short8, wf[ksl]);
            acc[0] = __builtin_amdgcn_mfma_f32_16x16x32_bf16(a0, bb, acc[0], 0, 0, 0);
            acc[1] = __builtin_amdgcn_mfma_f32_16x16x32_bf16(a1, bb, acc[1], 0, 0, 0);
        }
        __syncthreads();
        if (c < 63) {           // post-barrier B-frag load: consumed next body,
#pragma unroll                  // never drained in-flight by a barrier
            for (int ksl = 0; ksl < 4; ++ksl)
                wf[ksl] = wbase[(size_t)((c + 1) * 4 + ksl) * 64];
        }
    };

    for (int c = 0; c < 64; c += 2) {
        body(c, rpB);       // chunk c+1 (odd)  lives in slot 1
        body(c + 1, rpA);   // chunk c+2 (even) lives in slot 0
    }

    // epilogue: C/D col = lane&15, row = (lane>>4)*4 + r
    const int col = lane & 15, r0 = (lane >> 4) * 4;
#pragma unroll
    for (int h = 0; h < 2; ++h) {
        size_t ebase = e0 + (size_t)h * 16 + r0;
#pragma unroll
        for (int r = 0; r < 4; ++r)
            out[(ebase + r) * UNITS + wid * 16 + col] = acc[h][r];
    }
}

extern "C" void kernel_launch(void* const* d_in, const int* in_sizes, int n_in,
                              void* d_out, int out_size, void* d_ws, size_t ws_size,
                              hipStream_t stream) {
    const float* rbf = (const float*)d_in[0];
    const float* sph = (const float*)d_in[1];
    const float* m   = (const float*)d_in[2];
    const float* w   = (const float*)d_in[3];
    const int*   idr = (const int*)d_in[4];
    const int*   kix = (const int*)d_in[5];
    float* out = (float*)d_out;

    // ws: inv (1.28 MB, pad to 0x140000) | w2f (2 MB) | rpad (20.48 MB)
    int*   inv  = (int*)d_ws;
    uint4* w2f  = (uint4*)((char*)d_ws + 0x140000);
    uint4* rpad = (uint4*)((char*)d_ws + 0x340000);

    prep<<<SC_BLOCKS + W_BLOCKS + RP_BLOCKS, 256, 0, stream>>>(idr, kix, inv, w, w2f, rbf, rpad);
    fused_all<<<NEDGES / 32, 512, 0, stream>>>(sph, m, inv, w2f, rpad, out);
}